// Round 1
// baseline (957.923 us; speedup 1.0000x reference)
//
#include <hip/hip_runtime.h>
#include <hip/hip_bf16.h>

typedef __bf16 bf16x8 __attribute__((ext_vector_type(8)));
typedef __bf16 bf16x4 __attribute__((ext_vector_type(4)));
typedef float  f32x4  __attribute__((ext_vector_type(4)));

// ---------------- cast fp32 -> bf16, 8 elems/thread ----------------
__global__ void cast_f32_bf16(const float* __restrict__ src, __bf16* __restrict__ dst, int n8) {
    int i = blockIdx.x * 256 + threadIdx.x;
    if (i >= n8) return;
    const float4* s = (const float4*)src;
    float4 a = s[2 * i], b = s[2 * i + 1];
    bf16x8 o;
    o[0] = (__bf16)a.x; o[1] = (__bf16)a.y; o[2] = (__bf16)a.z; o[3] = (__bf16)a.w;
    o[4] = (__bf16)b.x; o[5] = (__bf16)b.y; o[6] = (__bf16)b.z; o[7] = (__bf16)b.w;
    ((bf16x8*)dst)[i] = o;
}

// ---------------- GEMM: C[M][N] = A[M][K] * Bm[N][K]^T (bf16 in, bf16/f32 out) ----
// 128x128 tile, BK=64, 256 thr (4 waves, 2x2), 16x16x32 bf16 MFMA, 4x4 frags/wave.
// LDS rows are 128B; XOR swizzle byte^=((row&7)<<4) on write AND read (rule #21).
template <int OUT_BF16>
__global__ __launch_bounds__(256)
void gemm_bt(const __bf16* __restrict__ A, const __bf16* __restrict__ Bm,
             void* __restrict__ Cout, int M, int N, int K) {
    __shared__ __bf16 As[128 * 64];
    __shared__ __bf16 Bs[128 * 64];
    const int tid = threadIdx.x;
    const int lane = tid & 63, wid = tid >> 6;
    const int g = lane >> 4, lq = lane & 15;
    const int wr = wid >> 1, wc = wid & 1;
    const size_t brow = (size_t)blockIdx.y * 128, bcol = (size_t)blockIdx.x * 128;
    f32x4 acc[4][4] = {};
    const int nkt = K >> 6;

    for (int kt = 0; kt < nkt; ++kt) {
        __syncthreads();
#pragma unroll
        for (int is = 0; is < 4; ++is) {
            int flat = is * 4096 + tid * 16;       // bytes within 16KB tile
            int row  = flat >> 7;                  // 128B per row (64 bf16)
            int colb = flat & 127;
            int sw   = colb ^ ((row & 7) << 4);
            int4 va = *(const int4*)((const char*)A + ((brow + row) * (size_t)K + (size_t)kt * 64) * 2 + colb);
            *(int4*)((char*)As + row * 128 + sw) = va;
            int4 vb = *(const int4*)((const char*)Bm + ((bcol + row) * (size_t)K + (size_t)kt * 64) * 2 + colb);
            *(int4*)((char*)Bs + row * 128 + sw) = vb;
        }
        __syncthreads();
#pragma unroll
        for (int ks = 0; ks < 2; ++ks) {
            bf16x8 af[4], bfr[4];
            const int kb = ks * 64 + g * 16;
#pragma unroll
            for (int i = 0; i < 4; ++i) {
                int row = wr * 64 + i * 16 + lq;
                af[i] = *(const bf16x8*)((const char*)As + row * 128 + (kb ^ ((row & 7) << 4)));
            }
#pragma unroll
            for (int j = 0; j < 4; ++j) {
                int row = wc * 64 + j * 16 + lq;
                bfr[j] = *(const bf16x8*)((const char*)Bs + row * 128 + (kb ^ ((row & 7) << 4)));
            }
#pragma unroll
            for (int i = 0; i < 4; ++i)
#pragma unroll
                for (int j = 0; j < 4; ++j)
                    acc[i][j] = __builtin_amdgcn_mfma_f32_16x16x32_bf16(af[i], bfr[j], acc[i][j], 0, 0, 0);
        }
    }
    // epilogue: C row = (lane>>4)*4+reg within frag (m89-verified), col = lane&15
#pragma unroll
    for (int i = 0; i < 4; ++i) {
#pragma unroll
        for (int r = 0; r < 4; ++r) {
            size_t row = brow + wr * 64 + i * 16 + g * 4 + r;
#pragma unroll
            for (int j = 0; j < 4; ++j) {
                size_t col = bcol + wc * 64 + j * 16 + lq;
                float v = acc[i][j][r];
                if (OUT_BF16) ((__bf16*)Cout)[row * N + col] = (__bf16)v;
                else          ((float*)Cout)[row * N + col] = v;
            }
        }
    }
}

// ---------------- V transpose: qkv V-part [b*S+t][5120+kh*128+d] -> vt[(b*8+kh)*128+d][t]
__global__ __launch_bounds__(256)
void transpose_v(const __bf16* __restrict__ qkv, __bf16* __restrict__ vt) {
    constexpr int S = 2048, QKVN = 6144;
    __shared__ __bf16 tile[64][72];
    const int tt = blockIdx.x;            // t tile (64 rows)
    const int yz = blockIdx.y;            // (b*8+kh)*2 + dh
    const int dh = yz & 1, bkh = yz >> 1;
    const int b = bkh >> 3, kh = bkh & 7;
    const int tid = threadIdx.x;
#pragma unroll
    for (int i = 0; i < 2; ++i) {
        int flat = i * 2048 + tid * 8;    // elems
        int r = flat >> 6, c0 = flat & 63;
        const __bf16* src = qkv + ((size_t)b * S + tt * 64 + r) * QKVN + 5120 + kh * 128 + dh * 64 + c0;
        *(bf16x8*)&tile[r][c0] = *(const bf16x8*)src;
    }
    __syncthreads();
#pragma unroll
    for (int i = 0; i < 2; ++i) {
        int flat = i * 2048 + tid * 8;
        int d = flat >> 6, t0 = flat & 63;
        bf16x8 pk;
#pragma unroll
        for (int e = 0; e < 8; ++e) pk[e] = tile[t0 + e][d];
        __bf16* dst = vt + ((size_t)(b * 8 + kh) * 128 + dh * 64 + d) * S + tt * 64 + t0;
        *(bf16x8*)dst = pk;
    }
}

// ---------------- flash attention (causal, GQA) ----------------
// grid: x = S/64 q-tiles, y = B*32 heads. 256 thr; wave w owns q rows w*16..w*16+15.
// Swapped QK^T: mfma(K,Q) -> lane holds S[q=lane&15][t]; softmax is lane-local + 2 shfl_xor.
__global__ __launch_bounds__(256)
void attn_kernel(const __bf16* __restrict__ qkv, const __bf16* __restrict__ vt,
                 __bf16* __restrict__ outb) {
    constexpr int S = 2048, D = 128, QKVN = 6144;
    const int qt = blockIdx.x;
    const int bh = blockIdx.y;
    const int b = bh >> 5, h = bh & 31;
    const int kh = h >> 2;
    const int tid = threadIdx.x, lane = tid & 63, w = tid >> 6;
    const int g = lane >> 4, lq = lane & 15;

    __shared__ __bf16 Ks[64 * 128];      // [t][d] rows 256B, swizzled
    __shared__ __bf16 Vs[128 * 64];      // [d][t] rows 128B, swizzled
    __shared__ __bf16 Ps[4][16 * 72];    // per-wave P, row stride 144B (conflict-free)

    // Q fragments, straight from global (L2-resident): q row = qt*64 + w*16 + lq
    const __bf16* qrow = qkv + ((size_t)b * S + qt * 64 + w * 16 + lq) * QKVN + h * D;
    bf16x8 qf[4];
#pragma unroll
    for (int ks = 0; ks < 4; ++ks) qf[ks] = *(const bf16x8*)(qrow + ks * 32 + g * 8);

    f32x4 acc_o[8] = {};
    float m_r = -1e30f, l_r = 0.f;
    const float scale = 0.088388347648318447f;   // 1/sqrt(128)
    const int qg = qt * 64 + w * 16 + lq;

    for (int kt = 0; kt <= qt; ++kt) {
        __syncthreads();
        // stage K tile [64][128] (rows 256B) with write-side swizzle
#pragma unroll
        for (int is = 0; is < 4; ++is) {
            int flat = is * 4096 + tid * 16;
            int row = flat >> 8, colb = flat & 255;
            int4 v = *(const int4*)((const char*)qkv +
                     (((size_t)b * S + kt * 64 + row) * QKVN + 4096 + kh * D) * 2 + colb);
            *(int4*)((char*)Ks + row * 256 + (colb ^ ((row & 7) << 4))) = v;
        }
        // stage V^T tile [128][64] (rows 128B) from pre-transposed vt
#pragma unroll
        for (int is = 0; is < 4; ++is) {
            int flat = is * 4096 + tid * 16;
            int d = flat >> 7, colb = flat & 127;
            int4 v = *(const int4*)((const char*)vt +
                     (((size_t)(b * 8 + kh) * D + d) * S + (size_t)kt * 64) * 2 + colb);
            *(int4*)((char*)Vs + d * 128 + (colb ^ ((d & 7) << 4))) = v;
        }
        __syncthreads();

        // swapped QK^T: sc[tb][r] = S[q=lq][t = kt*64 + tb*16 + g*4 + r]
        f32x4 sc[4];
#pragma unroll
        for (int tb = 0; tb < 4; ++tb) {
            f32x4 s = {0.f, 0.f, 0.f, 0.f};
            const int trow = tb * 16 + lq;
#pragma unroll
            for (int ks = 0; ks < 4; ++ks) {
                bf16x8 kf = *(const bf16x8*)((const char*)Ks + trow * 256 +
                                             ((ks * 64 + g * 16) ^ ((trow & 7) << 4)));
                s = __builtin_amdgcn_mfma_f32_16x16x32_bf16(kf, qf[ks], s, 0, 0, 0);
            }
            sc[tb] = s;
        }

        // scale + causal mask + online softmax (lane owns row q=lq)
        float p[4][4];
        float rowmax = -1e30f;
#pragma unroll
        for (int tb = 0; tb < 4; ++tb)
#pragma unroll
            for (int r = 0; r < 4; ++r) {
                int tg = kt * 64 + tb * 16 + g * 4 + r;
                float sv = sc[tb][r] * scale;
                sv = (tg <= qg) ? sv : -1e30f;
                p[tb][r] = sv;
                rowmax = fmaxf(rowmax, sv);
            }
        rowmax = fmaxf(rowmax, __shfl_xor(rowmax, 16));
        rowmax = fmaxf(rowmax, __shfl_xor(rowmax, 32));
        float m_new = fmaxf(m_r, rowmax);
        float alpha = __expf(m_r - m_new);
        float rowsum = 0.f;
#pragma unroll
        for (int tb = 0; tb < 4; ++tb)
#pragma unroll
            for (int r = 0; r < 4; ++r) {
                float e = __expf(p[tb][r] - m_new);
                p[tb][r] = e;
                rowsum += e;
            }
        rowsum += __shfl_xor(rowsum, 16);
        rowsum += __shfl_xor(rowsum, 32);
        l_r = l_r * alpha + rowsum;
        m_r = m_new;

        // rescale O (O rows are q=g*4+r; alpha lives at lane q=lq -> shuffle broadcast)
#pragma unroll
        for (int r = 0; r < 4; ++r) {
            float ar = __shfl(alpha, g * 4 + r);
#pragma unroll
            for (int nb = 0; nb < 8; ++nb) acc_o[nb][r] *= ar;
        }

        // P -> LDS (bf16), then read back as MFMA-A fragments
#pragma unroll
        for (int tb = 0; tb < 4; ++tb) {
            bf16x4 pk;
#pragma unroll
            for (int r = 0; r < 4; ++r) pk[r] = (__bf16)p[tb][r];
            *(bf16x4*)((char*)&Ps[w][0] + lq * 144 + (tb * 16 + g * 4) * 2) = pk;
        }
#pragma unroll
        for (int ks = 0; ks < 2; ++ks) {
            bf16x8 pa = *(const bf16x8*)((const char*)&Ps[w][0] + lq * 144 + ks * 64 + g * 16);
#pragma unroll
            for (int nb = 0; nb < 8; ++nb) {
                int d = nb * 16 + lq;
                bf16x8 vf = *(const bf16x8*)((const char*)Vs + d * 128 +
                                             ((ks * 64 + g * 16) ^ ((d & 7) << 4)));
                acc_o[nb] = __builtin_amdgcn_mfma_f32_16x16x32_bf16(pa, vf, acc_o[nb], 0, 0, 0);
            }
        }
    }

    // epilogue: O /= l, write bf16 [b*S+q][h*128+d]
    float rl = 1.f / l_r;
#pragma unroll
    for (int r = 0; r < 4; ++r) {
        float rr = __shfl(rl, g * 4 + r);
        size_t row = (size_t)b * S + qt * 64 + w * 16 + g * 4 + r;
        __bf16* orow = outb + row * 4096 + h * D;
#pragma unroll
        for (int nb = 0; nb < 8; ++nb)
            orow[nb * 16 + lq] = (__bf16)(acc_o[nb][r] * rr);
    }
}

// ---------------- launch ----------------
extern "C" void kernel_launch(void* const* d_in, const int* in_sizes, int n_in,
                              void* d_out, int out_size, void* d_ws, size_t ws_size,
                              hipStream_t stream) {
    (void)in_sizes; (void)n_in; (void)out_size; (void)ws_size;
    const float* q       = (const float*)d_in[0];
    const float* w_qkv   = (const float*)d_in[1];
    const float* w_dense = (const float*)d_in[2];
    float* out = (float*)d_out;
    char* ws = (char*)d_ws;

    __bf16* qbf      = (__bf16*)(ws);                 // 4096*4096      = 33,554,432 B
    __bf16* wqkvbf   = (__bf16*)(ws + 33554432ULL);   // 6144*4096      = 50,331,648 B
    __bf16* wdensebf = (__bf16*)(ws + 83886080ULL);   // 4096*4096      = 33,554,432 B
    __bf16* qkvbf    = (__bf16*)(ws + 117440512ULL);  // 4096*6144      = 50,331,648 B
    __bf16* vtbf     = (__bf16*)(ws + 167772160ULL);  // 2*8*128*2048   =  8,388,608 B
    __bf16* attnbf   = (__bf16*)(ws + 176160768ULL);  // 4096*4096      = 33,554,432 B
    // total ws use: 209,715,200 B

    cast_f32_bf16<<<8192, 256, 0, stream>>>(q, qbf, 2097152);
    cast_f32_bf16<<<12288, 256, 0, stream>>>(w_qkv, wqkvbf, 3145728);
    cast_f32_bf16<<<8192, 256, 0, stream>>>(w_dense, wdensebf, 2097152);

    gemm_bt<1><<<dim3(48, 32), 256, 0, stream>>>(qbf, wqkvbf, (void*)qkvbf, 4096, 6144, 4096);
    transpose_v<<<dim3(32, 32), 256, 0, stream>>>(qkvbf, vtbf);
    attn_kernel<<<dim3(32, 64), 256, 0, stream>>>(qkvbf, vtbf, attnbf);
    gemm_bt<0><<<dim3(32, 32), 256, 0, stream>>>(attnbf, wdensebf, (void*)out, 4096, 4096, 4096);
}